// Round 11
// baseline (1005.870 us; speedup 1.0000x reference)
//
#include <hip/hip_runtime.h>
#include <math.h>

#define TWO_PI_F 6.283185307179586f

typedef __fp16 half2_t __attribute__((ext_vector_type(2)));
typedef __fp16 half8_t __attribute__((ext_vector_type(8)));
typedef float  f32x4   __attribute__((ext_vector_type(4)));
typedef unsigned u32x2 __attribute__((ext_vector_type(2)));
typedef unsigned u32x4 __attribute__((ext_vector_type(4)));

// ---- d_ws layout (u32 units) ----
#define OFF_A1C   0      // [4 t][16 m15][2]  enc1 A compact
#define OFF_A2    128    // [4 (mt*2+kt)][64 lane][4 reg] enc2 A-frags
#define OFF_ATL   1152   // [64 lane][4 reg]  tail A-frag
#define OFF_ENCFB 1408   // [3] f32 folded tail bias (pad to 1424)
#define OFF_FP    1424   // [10][8][12] per-(layer,p) contiguous weight block:
//   {w0e,w0o,w1o,bhe,bho,m2e,m2o,a2e,a2o,m1,a1,pad} -> 3 x b128 per p
#define OFF_FS    2384   // [10][8] f32 scalars {B2fold,bmu1,ba2,ba1,LCe,pad,pad,pad}
#define OFF_FIN2  2464   // 2 f32: {bm0_9, c0_9}
#define FSTAGE    1042   // u32 staged to LDS in flow kernel (OFF_FP..)

__device__ __forceinline__ unsigned pack2(float a, float b) {
    half2_t h = __builtin_amdgcn_cvt_pkrtz(a, b);
    union { half2_t h; unsigned u; } cvt;
    cvt.h = h;
    return cvt.u;
}

__global__ __launch_bounds__(256)
void gsi_setup(const float* __restrict__ ew1, const float* __restrict__ ew2,
               const float* __restrict__ ew3, const float* __restrict__ eb3,
               const float* __restrict__ pw,  const float* __restrict__ pb,
               const float* __restrict__ fwh, const float* __restrict__ fbh,
               const float* __restrict__ fwmu, const float* __restrict__ fbmu,
               const float* __restrict__ fwa, const float* __restrict__ fba,
               unsigned* __restrict__ ws)
{
    int t = threadIdx.x;

    // enc1 A compact
    for (int idx = t; idx < 128; idx += 256) {
        int tt = idx >> 5, rest = idx & 31, m15 = rest >> 1, h = rest & 1;
        int f = 16 * tt + m15;
        ws[OFF_A1C + idx] = pack2(ew1[(2 * h) * 64 + f], ew1[(2 * h + 1) * 64 + f]);
    }
    // enc2 A-frags: c(q,j) = 32kt + 4q + (j&3) + 16*(j>>2)
    for (int idx = t; idx < 1024; idx += 256) {
        int r = idx & 3, l = (idx >> 2) & 63, f = idx >> 8;
        int mt = f >> 1, kt = f & 1, q = l >> 4, m = (l & 15) + 16 * mt;
        int j0 = 2 * r;
        int c0 = 32 * kt + 4 * q + (j0 & 3) + 16 * (j0 >> 2);
        ws[OFF_A2 + idx] = pack2(ew2[c0 * 32 + m], ew2[(c0 + 1) * 32 + m]);
    }
    // tail A-frag: Wf = ew3(32,8)@pw(8,3)
    for (int idx = t; idx < 256; idx += 256) {
        int lane = idx >> 2, r = idx & 3;
        int q = lane >> 4, m15 = lane & 15;
        unsigned v = 0;
        if (m15 < 3) {
            int j0 = 2 * r, j1 = 2 * r + 1;
            int k0 = 4 * q + (j0 & 3) + 16 * (j0 >> 2);
            int k1 = 4 * q + (j1 & 3) + 16 * (j1 >> 2);
            float w0 = 0.f, w1 = 0.f;
            for (int c = 0; c < 8; ++c) {
                w0 += ew3[k0 * 8 + c] * pw[c * 3 + m15];
                w1 += ew3[k1 * 8 + c] * pw[c * 3 + m15];
            }
            v = pack2(w0, w1);
        }
        ws[OFF_ATL + idx] = v;
    }
    if (t < 3) {
        float b = pb[t];
        for (int c = 0; c < 8; ++c) b += eb3[c] * pw[c * 3 + t];
        union { float f; unsigned u; } cvt; cvt.f = b;
        ws[OFF_ENCFB + t] = cvt.u;
    }

    // ---- flow per-(layer,p) contiguous blocks ----
    for (int idx = t; idx < 80; idx += 256) {
        int l = idx >> 3, p = idx & 7;
        unsigned* P = ws + OFF_FP + (l * 8 + p) * 12;
        float invc = (l == 0) ? 1.0f : expf(tanhf(fba[(l - 1) * 3 + 0]));
        P[0]  = pack2(fwh[l * 96 + 4 * p],          fwh[l * 96 + 4 * p + 2]);      // w0e
        P[1]  = pack2(fwh[l * 96 + 4 * p + 1],      fwh[l * 96 + 4 * p + 3]);      // w0o
        P[2]  = pack2(fwh[l * 96 + 32 + 4 * p + 1], fwh[l * 96 + 32 + 4 * p + 3]); // w1o
        P[3]  = pack2(fbh[l * 32 + 4 * p],          fbh[l * 32 + 4 * p + 2]);      // bhe
        P[4]  = pack2(fbh[l * 32 + 4 * p + 1],      fbh[l * 32 + 4 * p + 3]);      // bho
        P[5]  = pack2(fwmu[l * 96 + (4 * p) * 3 + 2] * invc,
                      fwmu[l * 96 + (4 * p + 2) * 3 + 2] * invc);                  // m2e
        P[6]  = pack2(fwmu[l * 96 + (4 * p + 1) * 3 + 2] * invc,
                      fwmu[l * 96 + (4 * p + 3) * 3 + 2] * invc);                  // m2o
        P[7]  = pack2(fwa[l * 96 + (4 * p) * 3 + 2],     fwa[l * 96 + (4 * p + 2) * 3 + 2]); // a2e
        P[8]  = pack2(fwa[l * 96 + (4 * p + 1) * 3 + 2], fwa[l * 96 + (4 * p + 3) * 3 + 2]); // a2o
        P[9]  = pack2(fwmu[l * 96 + (4 * p) * 3 + 1],    fwmu[l * 96 + (4 * p + 2) * 3 + 1]); // m1
        P[10] = pack2(fwa[l * 96 + (4 * p) * 3 + 1],     fwa[l * 96 + (4 * p + 2) * 3 + 1]);  // a1
        P[11] = 0;
    }
    if (t < 10) {
        int l = t;
        float c_prev  = (l == 0) ? 1.0f : expf(-tanhf(fba[(l - 1) * 3 + 0]));
        float bm0_prev = (l == 0) ? 0.0f : fbmu[(l - 1) * 3 + 0];
        float* F = (float*)(ws + OFF_FS + l * 8);
        F[0] = bm0_prev + fbmu[l * 3 + 2] / c_prev;   // B2fold
        F[1] = fbmu[l * 3 + 1];                        // bmu1
        F[2] = fba[l * 3 + 2];                         // ba2
        F[3] = fba[l * 3 + 1];                         // ba1
        F[4] = (l == 0) ? 0.0f : -tanhf(fba[(l - 1) * 3 + 0]);  // ln c0_{l-1}
        F[5] = 0.f; F[6] = 0.f; F[7] = 0.f;
    }
    if (t == 0) {
        float* F = (float*)(ws + OFF_FIN2);
        F[0] = fbmu[9 * 3 + 0];
        F[1] = expf(-tanhf(fba[9 * 3 + 0]));
    }
}

__device__ __forceinline__ float fast_rcp(float x) { return __builtin_amdgcn_rcpf(x); }

__device__ __forceinline__ float fast_tanh(float x) {
    float ax = fabsf(x);
    float t = __expf(-2.0f * ax);
    float r = (1.0f - t) * fast_rcp(1.0f + t);
    return copysignf(r, x);
}

__device__ __forceinline__ unsigned relu2u(float a, float b) {
    half2_t p = __builtin_amdgcn_cvt_pkrtz(a, b);
    half2_t z = {0, 0};
    union { half2_t h; unsigned u; } cvt;
    cvt.h = __builtin_elementwise_max(p, z);
    return cvt.u;
}

__device__ __forceinline__ half8_t mk8(unsigned a, unsigned b, unsigned c, unsigned d) {
    union { unsigned u[4]; half8_t v; } r;
    r.u[0] = a; r.u[1] = b; r.u[2] = c; r.u[3] = d;
    return r.v;
}

__device__ __forceinline__ half2_t h2(unsigned u) {
    union { unsigned u; half2_t h; } c; c.u = u; return c.h;
}

// ============ kernel 1: encoder (MFMA) -> x AoS in out (verbatim R10) ============
__global__ __launch_bounds__(256)
void gsi_enc(const float* __restrict__ states,
             const float* __restrict__ eb1, const float* __restrict__ eb2,
             const unsigned* __restrict__ ws,
             float* __restrict__ out, int n)
{
    int i = blockIdx.x * blockDim.x + threadIdx.x;
    int lane = threadIdx.x & 63;
    int wid = threadIdx.x >> 6;
    int rowbase = blockIdx.x * 256 + wid * 64;
    int q = lane >> 4;
    int l15 = lane & 15;
    bool q0 = (q == 0);

    const half8_t* a2p8  = (const half8_t*)(ws + OFF_A2);
    const float*   encfb = (const float*)(ws + OFF_ENCFB);

    half8_t aF1[4];
#pragma unroll
    for (int t = 0; t < 4; ++t) {
        u32x2 c = *(const u32x2*)(ws + OFF_A1C + t * 32 + l15 * 2);
        aF1[t] = mk8(q0 ? c.x : 0u, q0 ? c.y : 0u, 0u, 0u);
    }
    half8_t aF2[4];
#pragma unroll
    for (int f = 0; f < 4; ++f) aF2[f] = a2p8[f * 64 + lane];
    half8_t aFt = a2p8[4 * 64 + lane];

    f32x4 eb1c[4];
#pragma unroll
    for (int t = 0; t < 4; ++t) eb1c[t] = *(const f32x4*)(eb1 + 16 * t + 4 * q);
    f32x4 eb2c[2];
#pragma unroll
    for (int mt = 0; mt < 2; ++mt) eb2c[mt] = *(const f32x4*)(eb2 + 16 * mt + 4 * q);
    f32x4 tbias;
    {
        float e0 = encfb[0], e1 = encfb[1], e2 = encfb[2];
        tbias[0] = q0 ? e0 : 0.f;
        tbias[1] = q0 ? e1 : 0.f;
        tbias[2] = q0 ? e2 : 0.f;
        tbias[3] = 0.f;
    }

    f32x4 acct[4];
#pragma unroll
    for (int nt = 0; nt < 4; ++nt) {
        int row = rowbase + 16 * nt + l15;
        row = row < n ? row : (n - 1);
        const float4 s = reinterpret_cast<const float4*>(states)[row];
        unsigned p01 = pack2(s.x, s.y);
        unsigned p23 = pack2(s.z, s.w);
        half8_t b1 = mk8(q0 ? p01 : 0u, q0 ? p23 : 0u, 0u, 0u);

        f32x4 acc1[4];
#pragma unroll
        for (int t = 0; t < 4; ++t)
            acc1[t] = __builtin_amdgcn_mfma_f32_16x16x32_f16(aF1[t], b1, eb1c[t], 0, 0, 0);

        half8_t b2f0 = mk8(relu2u(acc1[0][0], acc1[0][1]), relu2u(acc1[0][2], acc1[0][3]),
                           relu2u(acc1[1][0], acc1[1][1]), relu2u(acc1[1][2], acc1[1][3]));
        half8_t b2f1 = mk8(relu2u(acc1[2][0], acc1[2][1]), relu2u(acc1[2][2], acc1[2][3]),
                           relu2u(acc1[3][0], acc1[3][1]), relu2u(acc1[3][2], acc1[3][3]));

        f32x4 acc2[2];
#pragma unroll
        for (int mt = 0; mt < 2; ++mt) {
            f32x4 a = __builtin_amdgcn_mfma_f32_16x16x32_f16(aF2[mt * 2 + 0], b2f0, eb2c[mt], 0, 0, 0);
            acc2[mt] = __builtin_amdgcn_mfma_f32_16x16x32_f16(aF2[mt * 2 + 1], b2f1, a, 0, 0, 0);
        }

        half8_t btl = mk8(relu2u(acc2[0][0], acc2[0][1]), relu2u(acc2[0][2], acc2[0][3]),
                          relu2u(acc2[1][0], acc2[1][1]), relu2u(acc2[1][2], acc2[1][3]));

        acct[nt] = __builtin_amdgcn_mfma_f32_16x16x32_f16(aFt, btl, tbias, 0, 0, 0);
    }

    {
        int paddr = l15 * 4;
        float xr[3];
#pragma unroll
        for (int m = 0; m < 3; ++m) {
            float p0 = __int_as_float(__builtin_amdgcn_ds_bpermute(paddr, __float_as_int(acct[0][m])));
            float p1 = __int_as_float(__builtin_amdgcn_ds_bpermute(paddr, __float_as_int(acct[1][m])));
            float p2 = __int_as_float(__builtin_amdgcn_ds_bpermute(paddr, __float_as_int(acct[2][m])));
            float p3 = __int_as_float(__builtin_amdgcn_ds_bpermute(paddr, __float_as_int(acct[3][m])));
            float lo = (lane & 32) ? p2 : p0;
            float hi = (lane & 32) ? p3 : p1;
            xr[m] = (lane & 16) ? hi : lo;
        }
        if (i < n) {
            out[3 * i + 0] = xr[0];
            out[3 * i + 1] = xr[1];
            out[3 * i + 2] = xr[2];
        }
    }
}

// ============ kernel 2: flow — 4 rows/thread, b128 weight reads ============
#define ROW_DECL(R) float x##R##0, x##R##1, x##R##2; \
                    float mu2##R, mu1##R, aa2##R, aa1##R; \
                    half2_t x##R##0d, x##R##1d;

#define ROW_HIDDEN(R) { \
    half2_t he = __builtin_elementwise_max(__builtin_elementwise_fma(x##R##0d, w0e, bhe), z); \
    half2_t ho = __builtin_elementwise_max(__builtin_elementwise_fma(x##R##0d, w0o, \
                     __builtin_elementwise_fma(x##R##1d, w1o, bho)), z); \
    mu2##R = __builtin_amdgcn_fdot2(he, m2e, mu2##R, false); \
    mu2##R = __builtin_amdgcn_fdot2(ho, m2o, mu2##R, false); \
    aa2##R = __builtin_amdgcn_fdot2(he, a2e, aa2##R, false); \
    aa2##R = __builtin_amdgcn_fdot2(ho, a2o, aa2##R, false); \
    mu1##R = __builtin_amdgcn_fdot2(he, m1w, mu1##R, false); \
    aa1##R = __builtin_amdgcn_fdot2(he, a1w, aa1##R, false); }

#define ROW_TAIL(R) { \
    float t1 = fast_tanh(aa1##R); \
    float t2 = fast_tanh(aa2##R); \
    float s2 = __expf(lce - t2); \
    float s1 = __expf(-t1); \
    float y2 = (x##R##2 - mu2##R) * s2; \
    float y1 = (x##R##1 - mu1##R) * s1; \
    x##R##2 = x##R##0; x##R##0 = y2; x##R##1 = y1; }

__global__ __launch_bounds__(256)
void gsi_flow(const unsigned* __restrict__ ws,
              float* __restrict__ out, int n, int nq)
{
    __shared__ __attribute__((aligned(16))) unsigned fl[FSTAGE];
    for (int idx = threadIdx.x; idx < FSTAGE; idx += 256) fl[idx] = ws[OFF_FP + idx];
    __syncthreads();

    int i = blockIdx.x * blockDim.x + threadIdx.x;
    if (i >= nq) return;
    int iA = i, iB = i + nq, iC = i + 2 * nq, iD = i + 3 * nq;
    bool gB = iB < n, gC = iC < n, gD = iD < n;
    int cB = gB ? iB : iA, cC = gC ? iC : iA, cD = gD ? iD : iA;

    ROW_DECL(A) ROW_DECL(B) ROW_DECL(C) ROW_DECL(D)

    xA0 = out[3 * iA + 0]; xA1 = out[3 * iA + 1]; xA2 = out[3 * iA + 2];
    xB0 = out[3 * cB + 0]; xB1 = out[3 * cB + 1]; xB2 = out[3 * cB + 2];
    xC0 = out[3 * cC + 0]; xC1 = out[3 * cC + 1]; xC2 = out[3 * cC + 2];
    xD0 = out[3 * cD + 0]; xD1 = out[3 * cD + 1]; xD2 = out[3 * cD + 2];

#pragma unroll
    for (int l = 0; l < 10; ++l) {
        const unsigned* Lp = fl + l * 96;
        const float* fs = (const float*)(fl + 960 + l * 8);
        float lce = fs[4];

        mu2A = fs[0]; mu1A = fs[1]; aa2A = fs[2]; aa1A = fs[3];
        mu2B = fs[0]; mu1B = fs[1]; aa2B = fs[2]; aa1B = fs[3];
        mu2C = fs[0]; mu1C = fs[1]; aa2C = fs[2]; aa1C = fs[3];
        mu2D = fs[0]; mu1D = fs[1]; aa2D = fs[2]; aa1D = fs[3];

        xA0d = __builtin_amdgcn_cvt_pkrtz(xA0, xA0); xA1d = __builtin_amdgcn_cvt_pkrtz(xA1, xA1);
        xB0d = __builtin_amdgcn_cvt_pkrtz(xB0, xB0); xB1d = __builtin_amdgcn_cvt_pkrtz(xB1, xB1);
        xC0d = __builtin_amdgcn_cvt_pkrtz(xC0, xC0); xC1d = __builtin_amdgcn_cvt_pkrtz(xC1, xC1);
        xD0d = __builtin_amdgcn_cvt_pkrtz(xD0, xD0); xD1d = __builtin_amdgcn_cvt_pkrtz(xD1, xD1);

        half2_t z = {0, 0};

#pragma unroll
        for (int p = 0; p < 8; ++p) {
            u32x4 wv0 = *(const u32x4*)(Lp + p * 12);
            u32x4 wv1 = *(const u32x4*)(Lp + p * 12 + 4);
            u32x4 wv2 = *(const u32x4*)(Lp + p * 12 + 8);
            half2_t w0e = h2(wv0.x), w0o = h2(wv0.y), w1o = h2(wv0.z), bhe = h2(wv0.w);
            half2_t bho = h2(wv1.x), m2e = h2(wv1.y), m2o = h2(wv1.z), a2e = h2(wv1.w);
            half2_t a2o = h2(wv2.x), m1w = h2(wv2.y), a1w = h2(wv2.z);

            ROW_HIDDEN(A) ROW_HIDDEN(B) ROW_HIDDEN(C) ROW_HIDDEN(D)
        }

        ROW_TAIL(A) ROW_TAIL(B) ROW_TAIL(C) ROW_TAIL(D)
    }

    // pending layer-9 affine on the dim-0 slot (now in x?2)
    {
        const float* fin = (const float*)(fl + 1040);
        xA2 = (xA2 - fin[0]) * fin[1];
        xB2 = (xB2 - fin[0]) * fin[1];
        xC2 = (xC2 - fin[0]) * fin[1];
        xD2 = (xD2 - fin[0]) * fin[1];
    }

#define ROW_STORE(R, idx, g) { \
    float u0 = fast_rcp(1.0f + __expf(-x##R##0)); \
    float u1 = fast_rcp(1.0f + __expf(-x##R##1)); \
    float u2 = fast_rcp(1.0f + __expf(-x##R##2)); \
    if (g) { out[3 * (idx) + 0] = TWO_PI_F * u0; out[3 * (idx) + 1] = u1; out[3 * (idx) + 2] = u2; } }

    ROW_STORE(A, iA, true)
    ROW_STORE(B, iB, gB)
    ROW_STORE(C, iC, gC)
    ROW_STORE(D, iD, gD)
#undef ROW_STORE
}

extern "C" void kernel_launch(void* const* d_in, const int* in_sizes, int n_in,
                              void* d_out, int out_size, void* d_ws, size_t ws_size,
                              hipStream_t stream) {
    const float* states = (const float*)d_in[0];
    const float* ew1  = (const float*)d_in[1];
    const float* eb1  = (const float*)d_in[2];
    const float* ew2  = (const float*)d_in[3];
    const float* eb2  = (const float*)d_in[4];
    const float* ew3  = (const float*)d_in[5];
    const float* eb3  = (const float*)d_in[6];
    const float* pw   = (const float*)d_in[7];
    const float* pb   = (const float*)d_in[8];
    const float* fwh  = (const float*)d_in[9];
    const float* fbh  = (const float*)d_in[10];
    const float* fwmu = (const float*)d_in[11];
    const float* fbmu = (const float*)d_in[12];
    const float* fwa  = (const float*)d_in[13];
    const float* fba  = (const float*)d_in[14];
    float* out = (float*)d_out;
    unsigned* ws = (unsigned*)d_ws;

    gsi_setup<<<1, 256, 0, stream>>>(ew1, ew2, ew3, eb3, pw, pb,
                                     fwh, fbh, fwmu, fbmu, fwa, fba, ws);

    int n = in_sizes[0] / 4;
    int grid = (n + 255) / 256;
    gsi_enc<<<grid, 256, 0, stream>>>(states, eb1, eb2, ws, out, n);

    int nq = (n + 3) / 4;
    int fgrid = (nq + 255) / 256;
    gsi_flow<<<fgrid, 256, 0, stream>>>(ws, out, n, nq);
}

// Round 12
// 110.644 us; speedup vs baseline: 9.0911x; 9.0911x over previous
//
#include <hip/hip_runtime.h>
#include <math.h>

#define TWO_PI_F 6.283185307179586f

typedef __fp16 half2_t __attribute__((ext_vector_type(2)));
typedef __fp16 half8_t __attribute__((ext_vector_type(8)));
typedef float  f32x4   __attribute__((ext_vector_type(4)));
typedef unsigned u32x2 __attribute__((ext_vector_type(2)));
typedef unsigned u32x4 __attribute__((ext_vector_type(4)));

// ---- d_ws layout (u32 units) ----
#define OFF_A1C   0      // [4 t][16 m15][2]  enc1 A compact
#define OFF_A2    128    // [4 (mt*2+kt)][64 lane][4 reg] enc2 A-frags
#define OFF_ATL   1152   // [64 lane][4 reg]  tail A-frag
#define OFF_ENCFB 1408   // [3] f32 folded tail bias (pad to 1424)
#define OFF_FP    1424   // [10][8][12] per-(layer,p) contiguous weight block:
//   {w0e,w0o,w1o,bhe,bho,m2e,m2o,a2e,a2o,m1,a1,pad} -> 3 x b128 per p
#define OFF_FS    2384   // [10][8] f32 scalars {B2fold,bmu1,ba2,ba1,LCe,pad,pad,pad}
#define OFF_FIN2  2464   // 2 f32: {bm0_9, c0_9}
#define FSTAGE    1042   // u32 staged to LDS in flow kernel (OFF_FP..)

__device__ __forceinline__ unsigned pack2(float a, float b) {
    half2_t h = __builtin_amdgcn_cvt_pkrtz(a, b);
    union { half2_t h; unsigned u; } cvt;
    cvt.h = h;
    return cvt.u;
}

__global__ __launch_bounds__(256)
void gsi_setup(const float* __restrict__ ew1, const float* __restrict__ ew2,
               const float* __restrict__ ew3, const float* __restrict__ eb3,
               const float* __restrict__ pw,  const float* __restrict__ pb,
               const float* __restrict__ fwh, const float* __restrict__ fbh,
               const float* __restrict__ fwmu, const float* __restrict__ fbmu,
               const float* __restrict__ fwa, const float* __restrict__ fba,
               unsigned* __restrict__ ws)
{
    int t = threadIdx.x;

    // enc1 A compact
    for (int idx = t; idx < 128; idx += 256) {
        int tt = idx >> 5, rest = idx & 31, m15 = rest >> 1, h = rest & 1;
        int f = 16 * tt + m15;
        ws[OFF_A1C + idx] = pack2(ew1[(2 * h) * 64 + f], ew1[(2 * h + 1) * 64 + f]);
    }
    // enc2 A-frags: c(q,j) = 32kt + 4q + (j&3) + 16*(j>>2)
    for (int idx = t; idx < 1024; idx += 256) {
        int r = idx & 3, l = (idx >> 2) & 63, f = idx >> 8;
        int mt = f >> 1, kt = f & 1, q = l >> 4, m = (l & 15) + 16 * mt;
        int j0 = 2 * r;
        int c0 = 32 * kt + 4 * q + (j0 & 3) + 16 * (j0 >> 2);
        ws[OFF_A2 + idx] = pack2(ew2[c0 * 32 + m], ew2[(c0 + 1) * 32 + m]);
    }
    // tail A-frag: Wf = ew3(32,8)@pw(8,3)
    for (int idx = t; idx < 256; idx += 256) {
        int lane = idx >> 2, r = idx & 3;
        int q = lane >> 4, m15 = lane & 15;
        unsigned v = 0;
        if (m15 < 3) {
            int j0 = 2 * r, j1 = 2 * r + 1;
            int k0 = 4 * q + (j0 & 3) + 16 * (j0 >> 2);
            int k1 = 4 * q + (j1 & 3) + 16 * (j1 >> 2);
            float w0 = 0.f, w1 = 0.f;
            for (int c = 0; c < 8; ++c) {
                w0 += ew3[k0 * 8 + c] * pw[c * 3 + m15];
                w1 += ew3[k1 * 8 + c] * pw[c * 3 + m15];
            }
            v = pack2(w0, w1);
        }
        ws[OFF_ATL + idx] = v;
    }
    if (t < 3) {
        float b = pb[t];
        for (int c = 0; c < 8; ++c) b += eb3[c] * pw[c * 3 + t];
        union { float f; unsigned u; } cvt; cvt.f = b;
        ws[OFF_ENCFB + t] = cvt.u;
    }

    // ---- flow per-(layer,p) contiguous blocks ----
    for (int idx = t; idx < 80; idx += 256) {
        int l = idx >> 3, p = idx & 7;
        unsigned* P = ws + OFF_FP + (l * 8 + p) * 12;
        float invc = (l == 0) ? 1.0f : expf(tanhf(fba[(l - 1) * 3 + 0]));
        P[0]  = pack2(fwh[l * 96 + 4 * p],          fwh[l * 96 + 4 * p + 2]);      // w0e
        P[1]  = pack2(fwh[l * 96 + 4 * p + 1],      fwh[l * 96 + 4 * p + 3]);      // w0o
        P[2]  = pack2(fwh[l * 96 + 32 + 4 * p + 1], fwh[l * 96 + 32 + 4 * p + 3]); // w1o
        P[3]  = pack2(fbh[l * 32 + 4 * p],          fbh[l * 32 + 4 * p + 2]);      // bhe
        P[4]  = pack2(fbh[l * 32 + 4 * p + 1],      fbh[l * 32 + 4 * p + 3]);      // bho
        P[5]  = pack2(fwmu[l * 96 + (4 * p) * 3 + 2] * invc,
                      fwmu[l * 96 + (4 * p + 2) * 3 + 2] * invc);                  // m2e
        P[6]  = pack2(fwmu[l * 96 + (4 * p + 1) * 3 + 2] * invc,
                      fwmu[l * 96 + (4 * p + 3) * 3 + 2] * invc);                  // m2o
        P[7]  = pack2(fwa[l * 96 + (4 * p) * 3 + 2],     fwa[l * 96 + (4 * p + 2) * 3 + 2]); // a2e
        P[8]  = pack2(fwa[l * 96 + (4 * p + 1) * 3 + 2], fwa[l * 96 + (4 * p + 3) * 3 + 2]); // a2o
        P[9]  = pack2(fwmu[l * 96 + (4 * p) * 3 + 1],    fwmu[l * 96 + (4 * p + 2) * 3 + 1]); // m1
        P[10] = pack2(fwa[l * 96 + (4 * p) * 3 + 1],     fwa[l * 96 + (4 * p + 2) * 3 + 1]);  // a1
        P[11] = 0;
    }
    if (t < 10) {
        int l = t;
        float c_prev  = (l == 0) ? 1.0f : expf(-tanhf(fba[(l - 1) * 3 + 0]));
        float bm0_prev = (l == 0) ? 0.0f : fbmu[(l - 1) * 3 + 0];
        float* F = (float*)(ws + OFF_FS + l * 8);
        F[0] = bm0_prev + fbmu[l * 3 + 2] / c_prev;   // B2fold
        F[1] = fbmu[l * 3 + 1];                        // bmu1
        F[2] = fba[l * 3 + 2];                         // ba2
        F[3] = fba[l * 3 + 1];                         // ba1
        F[4] = (l == 0) ? 0.0f : -tanhf(fba[(l - 1) * 3 + 0]);  // ln c0_{l-1}
        F[5] = 0.f; F[6] = 0.f; F[7] = 0.f;
    }
    if (t == 0) {
        float* F = (float*)(ws + OFF_FIN2);
        F[0] = fbmu[9 * 3 + 0];
        F[1] = expf(-tanhf(fba[9 * 3 + 0]));
    }
}

__device__ __forceinline__ float fast_rcp(float x) { return __builtin_amdgcn_rcpf(x); }

__device__ __forceinline__ float fast_tanh(float x) {
    float ax = fabsf(x);
    float t = __expf(-2.0f * ax);
    float r = (1.0f - t) * fast_rcp(1.0f + t);
    return copysignf(r, x);
}

__device__ __forceinline__ unsigned relu2u(float a, float b) {
    half2_t p = __builtin_amdgcn_cvt_pkrtz(a, b);
    half2_t z = {0, 0};
    union { half2_t h; unsigned u; } cvt;
    cvt.h = __builtin_elementwise_max(p, z);
    return cvt.u;
}

__device__ __forceinline__ half8_t mk8(unsigned a, unsigned b, unsigned c, unsigned d) {
    union { unsigned u[4]; half8_t v; } r;
    r.u[0] = a; r.u[1] = b; r.u[2] = c; r.u[3] = d;
    return r.v;
}

__device__ __forceinline__ half2_t h2(unsigned u) {
    union { unsigned u; half2_t h; } c; c.u = u; return c.h;
}

// ============ kernel 1: encoder (MFMA) -> x AoS in out (verbatim R10) ============
__global__ __launch_bounds__(256)
void gsi_enc(const float* __restrict__ states,
             const float* __restrict__ eb1, const float* __restrict__ eb2,
             const unsigned* __restrict__ ws,
             float* __restrict__ out, int n)
{
    int i = blockIdx.x * blockDim.x + threadIdx.x;
    int lane = threadIdx.x & 63;
    int wid = threadIdx.x >> 6;
    int rowbase = blockIdx.x * 256 + wid * 64;
    int q = lane >> 4;
    int l15 = lane & 15;
    bool q0 = (q == 0);

    const half8_t* a2p8  = (const half8_t*)(ws + OFF_A2);
    const float*   encfb = (const float*)(ws + OFF_ENCFB);

    half8_t aF1[4];
#pragma unroll
    for (int t = 0; t < 4; ++t) {
        u32x2 c = *(const u32x2*)(ws + OFF_A1C + t * 32 + l15 * 2);
        aF1[t] = mk8(q0 ? c.x : 0u, q0 ? c.y : 0u, 0u, 0u);
    }
    half8_t aF2[4];
#pragma unroll
    for (int f = 0; f < 4; ++f) aF2[f] = a2p8[f * 64 + lane];
    half8_t aFt = a2p8[4 * 64 + lane];

    f32x4 eb1c[4];
#pragma unroll
    for (int t = 0; t < 4; ++t) eb1c[t] = *(const f32x4*)(eb1 + 16 * t + 4 * q);
    f32x4 eb2c[2];
#pragma unroll
    for (int mt = 0; mt < 2; ++mt) eb2c[mt] = *(const f32x4*)(eb2 + 16 * mt + 4 * q);
    f32x4 tbias;
    {
        float e0 = encfb[0], e1 = encfb[1], e2 = encfb[2];
        tbias[0] = q0 ? e0 : 0.f;
        tbias[1] = q0 ? e1 : 0.f;
        tbias[2] = q0 ? e2 : 0.f;
        tbias[3] = 0.f;
    }

    f32x4 acct[4];
#pragma unroll
    for (int nt = 0; nt < 4; ++nt) {
        int row = rowbase + 16 * nt + l15;
        row = row < n ? row : (n - 1);
        const float4 s = reinterpret_cast<const float4*>(states)[row];
        unsigned p01 = pack2(s.x, s.y);
        unsigned p23 = pack2(s.z, s.w);
        half8_t b1 = mk8(q0 ? p01 : 0u, q0 ? p23 : 0u, 0u, 0u);

        f32x4 acc1[4];
#pragma unroll
        for (int t = 0; t < 4; ++t)
            acc1[t] = __builtin_amdgcn_mfma_f32_16x16x32_f16(aF1[t], b1, eb1c[t], 0, 0, 0);

        half8_t b2f0 = mk8(relu2u(acc1[0][0], acc1[0][1]), relu2u(acc1[0][2], acc1[0][3]),
                           relu2u(acc1[1][0], acc1[1][1]), relu2u(acc1[1][2], acc1[1][3]));
        half8_t b2f1 = mk8(relu2u(acc1[2][0], acc1[2][1]), relu2u(acc1[2][2], acc1[2][3]),
                           relu2u(acc1[3][0], acc1[3][1]), relu2u(acc1[3][2], acc1[3][3]));

        f32x4 acc2[2];
#pragma unroll
        for (int mt = 0; mt < 2; ++mt) {
            f32x4 a = __builtin_amdgcn_mfma_f32_16x16x32_f16(aF2[mt * 2 + 0], b2f0, eb2c[mt], 0, 0, 0);
            acc2[mt] = __builtin_amdgcn_mfma_f32_16x16x32_f16(aF2[mt * 2 + 1], b2f1, a, 0, 0, 0);
        }

        half8_t btl = mk8(relu2u(acc2[0][0], acc2[0][1]), relu2u(acc2[0][2], acc2[0][3]),
                          relu2u(acc2[1][0], acc2[1][1]), relu2u(acc2[1][2], acc2[1][3]));

        acct[nt] = __builtin_amdgcn_mfma_f32_16x16x32_f16(aFt, btl, tbias, 0, 0, 0);
    }

    {
        int paddr = l15 * 4;
        float xr[3];
#pragma unroll
        for (int m = 0; m < 3; ++m) {
            float p0 = __int_as_float(__builtin_amdgcn_ds_bpermute(paddr, __float_as_int(acct[0][m])));
            float p1 = __int_as_float(__builtin_amdgcn_ds_bpermute(paddr, __float_as_int(acct[1][m])));
            float p2 = __int_as_float(__builtin_amdgcn_ds_bpermute(paddr, __float_as_int(acct[2][m])));
            float p3 = __int_as_float(__builtin_amdgcn_ds_bpermute(paddr, __float_as_int(acct[3][m])));
            float lo = (lane & 32) ? p2 : p0;
            float hi = (lane & 32) ? p3 : p1;
            xr[m] = (lane & 16) ? hi : lo;
        }
        if (i < n) {
            out[3 * i + 0] = xr[0];
            out[3 * i + 1] = xr[1];
            out[3 * i + 2] = xr[2];
        }
    }
}

// ============ kernel 2: flow — 2 rows/thread, b128 reads, bounded unroll ============
#define ROW_DECL(R) float x##R##0, x##R##1, x##R##2; \
                    float mu2##R, mu1##R, aa2##R, aa1##R; \
                    half2_t x##R##0d, x##R##1d;

#define ROW_HIDDEN(R) { \
    half2_t he = __builtin_elementwise_max(__builtin_elementwise_fma(x##R##0d, w0e, bhe), z); \
    half2_t ho = __builtin_elementwise_max(__builtin_elementwise_fma(x##R##0d, w0o, \
                     __builtin_elementwise_fma(x##R##1d, w1o, bho)), z); \
    mu2##R = __builtin_amdgcn_fdot2(he, m2e, mu2##R, false); \
    mu2##R = __builtin_amdgcn_fdot2(ho, m2o, mu2##R, false); \
    aa2##R = __builtin_amdgcn_fdot2(he, a2e, aa2##R, false); \
    aa2##R = __builtin_amdgcn_fdot2(ho, a2o, aa2##R, false); \
    mu1##R = __builtin_amdgcn_fdot2(he, m1w, mu1##R, false); \
    aa1##R = __builtin_amdgcn_fdot2(he, a1w, aa1##R, false); }

#define ROW_TAIL(R) { \
    float t1 = fast_tanh(aa1##R); \
    float t2 = fast_tanh(aa2##R); \
    float s2 = __expf(lce - t2); \
    float s1 = __expf(-t1); \
    float y2 = (x##R##2 - mu2##R) * s2; \
    float y1 = (x##R##1 - mu1##R) * s1; \
    x##R##2 = x##R##0; x##R##0 = y2; x##R##1 = y1; }

__global__ __launch_bounds__(256)
void gsi_flow(const unsigned* __restrict__ ws,
              float* __restrict__ out, int n, int nh)
{
    __shared__ __attribute__((aligned(16))) unsigned fl[FSTAGE];
    for (int idx = threadIdx.x; idx < FSTAGE; idx += 256) fl[idx] = ws[OFF_FP + idx];
    __syncthreads();

    int i = blockIdx.x * blockDim.x + threadIdx.x;
    if (i >= nh) return;
    int iA = i, iB = i + nh;
    bool gB = iB < n;
    int cB = gB ? iB : iA;

    ROW_DECL(A) ROW_DECL(B)

    xA0 = out[3 * iA + 0]; xA1 = out[3 * iA + 1]; xA2 = out[3 * iA + 2];
    xB0 = out[3 * cB + 0]; xB1 = out[3 * cB + 1]; xB2 = out[3 * cB + 2];

#pragma unroll 1
    for (int l = 0; l < 10; ++l) {
        const unsigned* Lp = fl + l * 96;
        const float* fs = (const float*)(fl + 960 + l * 8);
        float lce = fs[4];

        mu2A = fs[0]; mu1A = fs[1]; aa2A = fs[2]; aa1A = fs[3];
        mu2B = fs[0]; mu1B = fs[1]; aa2B = fs[2]; aa1B = fs[3];

        xA0d = __builtin_amdgcn_cvt_pkrtz(xA0, xA0); xA1d = __builtin_amdgcn_cvt_pkrtz(xA1, xA1);
        xB0d = __builtin_amdgcn_cvt_pkrtz(xB0, xB0); xB1d = __builtin_amdgcn_cvt_pkrtz(xB1, xB1);

        half2_t z = {0, 0};

#pragma unroll
        for (int p = 0; p < 8; ++p) {
            u32x4 wv0 = *(const u32x4*)(Lp + p * 12);
            u32x4 wv1 = *(const u32x4*)(Lp + p * 12 + 4);
            u32x4 wv2 = *(const u32x4*)(Lp + p * 12 + 8);
            half2_t w0e = h2(wv0.x), w0o = h2(wv0.y), w1o = h2(wv0.z), bhe = h2(wv0.w);
            half2_t bho = h2(wv1.x), m2e = h2(wv1.y), m2o = h2(wv1.z), a2e = h2(wv1.w);
            half2_t a2o = h2(wv2.x), m1w = h2(wv2.y), a1w = h2(wv2.z);

            ROW_HIDDEN(A) ROW_HIDDEN(B)
        }

        ROW_TAIL(A) ROW_TAIL(B)
    }

    // pending layer-9 affine on the dim-0 slot (now in x?2)
    {
        const float* fin = (const float*)(fl + 1040);
        xA2 = (xA2 - fin[0]) * fin[1];
        xB2 = (xB2 - fin[0]) * fin[1];
    }

#define ROW_STORE(R, idx, g) { \
    float u0 = fast_rcp(1.0f + __expf(-x##R##0)); \
    float u1 = fast_rcp(1.0f + __expf(-x##R##1)); \
    float u2 = fast_rcp(1.0f + __expf(-x##R##2)); \
    if (g) { out[3 * (idx) + 0] = TWO_PI_F * u0; out[3 * (idx) + 1] = u1; out[3 * (idx) + 2] = u2; } }

    ROW_STORE(A, iA, true)
    ROW_STORE(B, iB, gB)
#undef ROW_STORE
}

extern "C" void kernel_launch(void* const* d_in, const int* in_sizes, int n_in,
                              void* d_out, int out_size, void* d_ws, size_t ws_size,
                              hipStream_t stream) {
    const float* states = (const float*)d_in[0];
    const float* ew1  = (const float*)d_in[1];
    const float* eb1  = (const float*)d_in[2];
    const float* ew2  = (const float*)d_in[3];
    const float* eb2  = (const float*)d_in[4];
    const float* ew3  = (const float*)d_in[5];
    const float* eb3  = (const float*)d_in[6];
    const float* pw   = (const float*)d_in[7];
    const float* pb   = (const float*)d_in[8];
    const float* fwh  = (const float*)d_in[9];
    const float* fbh  = (const float*)d_in[10];
    const float* fwmu = (const float*)d_in[11];
    const float* fbmu = (const float*)d_in[12];
    const float* fwa  = (const float*)d_in[13];
    const float* fba  = (const float*)d_in[14];
    float* out = (float*)d_out;
    unsigned* ws = (unsigned*)d_ws;

    gsi_setup<<<1, 256, 0, stream>>>(ew1, ew2, ew3, eb3, pw, pb,
                                     fwh, fbh, fwmu, fbmu, fwa, fba, ws);

    int n = in_sizes[0] / 4;
    int grid = (n + 255) / 256;
    gsi_enc<<<grid, 256, 0, stream>>>(states, eb1, eb2, ws, out, n);

    int nh = (n + 1) / 2;
    int fgrid = (nh + 255) / 256;
    gsi_flow<<<fgrid, 256, 0, stream>>>(ws, out, n, nh);
}

// Round 13
// 98.477 us; speedup vs baseline: 10.2143x; 1.1236x over previous
//
#include <hip/hip_runtime.h>
#include <math.h>

#define TWO_PI_F 6.283185307179586f

typedef __fp16 half2_t __attribute__((ext_vector_type(2)));
typedef __fp16 half8_t __attribute__((ext_vector_type(8)));
typedef float  f32x4   __attribute__((ext_vector_type(4)));
typedef unsigned u32x2 __attribute__((ext_vector_type(2)));

// ---- d_ws layout (u32 units) ----
#define OFF_A1C   0      // [4 t][16 m15][2]  enc1 A compact
#define OFF_A2    128    // [4 (mt*2+kt)][64 lane][4 reg] enc2 A-frags
#define OFF_ATL   1152   // [64 lane][4 reg]  tail A-frag
#define OFF_ENCFB 1408   // [3] f32 folded tail bias (pad to 1424)
#define OFF_FL    1424   // [10][80] per-layer flow weights (SGPR-resident):
//   +0  w0e[8]  +8 w0o[8]  +16 w1o[8]  +24 m2e[8]  +32 m2o[8]
//   +40 a2e[8]  +48 a2o[8] +56 m1[8]   +64 a1[8]   +72 pad
#define OFF_FB    2224   // [10][24]: bhe[8], bho[8], f32{B2fold,bmu1,ba2,ba1,LCe}+pad
#define OFF_FIN   2464   // 2 f32: {bm0_9, c0_9}

__device__ __forceinline__ unsigned pack2(float a, float b) {
    half2_t h = __builtin_amdgcn_cvt_pkrtz(a, b);
    union { half2_t h; unsigned u; } cvt;
    cvt.h = h;
    return cvt.u;
}

__global__ __launch_bounds__(256)
void gsi_setup(const float* __restrict__ ew1, const float* __restrict__ ew2,
               const float* __restrict__ ew3, const float* __restrict__ eb3,
               const float* __restrict__ pw,  const float* __restrict__ pb,
               const float* __restrict__ fwh, const float* __restrict__ fbh,
               const float* __restrict__ fwmu, const float* __restrict__ fbmu,
               const float* __restrict__ fwa, const float* __restrict__ fba,
               unsigned* __restrict__ ws)
{
    int t = threadIdx.x;

    // enc1 A compact
    for (int idx = t; idx < 128; idx += 256) {
        int tt = idx >> 5, rest = idx & 31, m15 = rest >> 1, h = rest & 1;
        int f = 16 * tt + m15;
        ws[OFF_A1C + idx] = pack2(ew1[(2 * h) * 64 + f], ew1[(2 * h + 1) * 64 + f]);
    }
    // enc2 A-frags: c(q,j) = 32kt + 4q + (j&3) + 16*(j>>2)
    for (int idx = t; idx < 1024; idx += 256) {
        int r = idx & 3, l = (idx >> 2) & 63, f = idx >> 8;
        int mt = f >> 1, kt = f & 1, q = l >> 4, m = (l & 15) + 16 * mt;
        int j0 = 2 * r;
        int c0 = 32 * kt + 4 * q + (j0 & 3) + 16 * (j0 >> 2);
        ws[OFF_A2 + idx] = pack2(ew2[c0 * 32 + m], ew2[(c0 + 1) * 32 + m]);
    }
    // tail A-frag: Wf = ew3(32,8)@pw(8,3)
    for (int idx = t; idx < 256; idx += 256) {
        int lane = idx >> 2, r = idx & 3;
        int q = lane >> 4, m15 = lane & 15;
        unsigned v = 0;
        if (m15 < 3) {
            int j0 = 2 * r, j1 = 2 * r + 1;
            int k0 = 4 * q + (j0 & 3) + 16 * (j0 >> 2);
            int k1 = 4 * q + (j1 & 3) + 16 * (j1 >> 2);
            float w0 = 0.f, w1 = 0.f;
            for (int c = 0; c < 8; ++c) {
                w0 += ew3[k0 * 8 + c] * pw[c * 3 + m15];
                w1 += ew3[k1 * 8 + c] * pw[c * 3 + m15];
            }
            v = pack2(w0, w1);
        }
        ws[OFF_ATL + idx] = v;
    }
    if (t < 3) {
        float b = pb[t];
        for (int c = 0; c < 8; ++c) b += eb3[c] * pw[c * 3 + t];
        union { float f; unsigned u; } cvt; cvt.f = b;
        ws[OFF_ENCFB + t] = cvt.u;
    }

    // ---- flow weights (even/odd split; mu2 pre-scaled by 1/c0_{l-1}) ----
    for (int idx = t; idx < 80; idx += 256) {
        int l = idx >> 3, p = idx & 7;
        unsigned* L = ws + OFF_FL + l * 80;
        float invc = (l == 0) ? 1.0f : expf(tanhf(fba[(l - 1) * 3 + 0]));
        L[p]      = pack2(fwh[l * 96 + 4 * p],          fwh[l * 96 + 4 * p + 2]);
        L[8 + p]  = pack2(fwh[l * 96 + 4 * p + 1],      fwh[l * 96 + 4 * p + 3]);
        L[16 + p] = pack2(fwh[l * 96 + 32 + 4 * p + 1], fwh[l * 96 + 32 + 4 * p + 3]);
        L[24 + p] = pack2(fwmu[l * 96 + (4 * p) * 3 + 2] * invc,
                          fwmu[l * 96 + (4 * p + 2) * 3 + 2] * invc);
        L[32 + p] = pack2(fwmu[l * 96 + (4 * p + 1) * 3 + 2] * invc,
                          fwmu[l * 96 + (4 * p + 3) * 3 + 2] * invc);
        L[40 + p] = pack2(fwa[l * 96 + (4 * p) * 3 + 2],     fwa[l * 96 + (4 * p + 2) * 3 + 2]);
        L[48 + p] = pack2(fwa[l * 96 + (4 * p + 1) * 3 + 2], fwa[l * 96 + (4 * p + 3) * 3 + 2]);
        L[56 + p] = pack2(fwmu[l * 96 + (4 * p) * 3 + 1],    fwmu[l * 96 + (4 * p + 2) * 3 + 1]);
        L[64 + p] = pack2(fwa[l * 96 + (4 * p) * 3 + 1],     fwa[l * 96 + (4 * p + 2) * 3 + 1]);
    }
    // ---- LDS-staged per-layer block: biases + accumulator inits ----
    for (int idx = t; idx < 160; idx += 256) {
        int l = idx >> 4, j = idx & 15, p = j & 7;
        unsigned v = (j < 8) ? pack2(fbh[l * 32 + 4 * p],     fbh[l * 32 + 4 * p + 2])
                             : pack2(fbh[l * 32 + 4 * p + 1], fbh[l * 32 + 4 * p + 3]);
        ws[OFF_FB + l * 24 + j] = v;
    }
    if (t < 10) {
        int l = t;
        float c_prev  = (l == 0) ? 1.0f : expf(-tanhf(fba[(l - 1) * 3 + 0]));
        float bm0_prev = (l == 0) ? 0.0f : fbmu[(l - 1) * 3 + 0];
        float* F = (float*)(ws + OFF_FB + l * 24 + 16);
        F[0] = bm0_prev + fbmu[l * 3 + 2] / c_prev;   // B2fold
        F[1] = fbmu[l * 3 + 1];                        // bmu1
        F[2] = fba[l * 3 + 2];                         // ba2
        F[3] = fba[l * 3 + 1];                         // ba1
        F[4] = (l == 0) ? 0.0f : -tanhf(fba[(l - 1) * 3 + 0]);  // ln c0_{l-1}
    }
    if (t == 0) {
        float* F = (float*)(ws + OFF_FIN);
        F[0] = fbmu[9 * 3 + 0];
        F[1] = expf(-tanhf(fba[9 * 3 + 0]));
    }
}

__device__ __forceinline__ float fast_rcp(float x) { return __builtin_amdgcn_rcpf(x); }

__device__ __forceinline__ float fast_tanh(float x) {
    float ax = fabsf(x);
    float t = __expf(-2.0f * ax);
    float r = (1.0f - t) * fast_rcp(1.0f + t);
    return copysignf(r, x);
}

__device__ __forceinline__ unsigned relu2u(float a, float b) {
    half2_t p = __builtin_amdgcn_cvt_pkrtz(a, b);
    half2_t z = {0, 0};
    union { half2_t h; unsigned u; } cvt;
    cvt.h = __builtin_elementwise_max(p, z);
    return cvt.u;
}

__device__ __forceinline__ half8_t mk8(unsigned a, unsigned b, unsigned c, unsigned d) {
    union { unsigned u[4]; half8_t v; } r;
    r.u[0] = a; r.u[1] = b; r.u[2] = c; r.u[3] = d;
    return r.v;
}

__global__ __launch_bounds__(256)
void gsi_kernel(const float* __restrict__ states,
                const float* __restrict__ eb1, const float* __restrict__ eb2,
                const unsigned* __restrict__ ws,
                float* __restrict__ out, int n)
{
    __shared__ unsigned flds[240];
    if (threadIdx.x < 240) flds[threadIdx.x] = ws[OFF_FB + threadIdx.x];
    __syncthreads();

    int i = blockIdx.x * blockDim.x + threadIdx.x;
    int lane = threadIdx.x & 63;
    int wid = threadIdx.x >> 6;
    int rowbase = blockIdx.x * 256 + wid * 64;
    int q = lane >> 4;
    int l15 = lane & 15;
    bool q0 = (q == 0);

    const half8_t* a2p8  = (const half8_t*)(ws + OFF_A2);
    const float*   encfb = (const float*)(ws + OFF_ENCFB);

    // ---- persistent fragments ----
    half8_t aF1[4];
#pragma unroll
    for (int t = 0; t < 4; ++t) {
        u32x2 c = *(const u32x2*)(ws + OFF_A1C + t * 32 + l15 * 2);
        aF1[t] = mk8(q0 ? c.x : 0u, q0 ? c.y : 0u, 0u, 0u);
    }
    half8_t aF2[4];
#pragma unroll
    for (int f = 0; f < 4; ++f) aF2[f] = a2p8[f * 64 + lane];
    half8_t aFt = a2p8[4 * 64 + lane];

    f32x4 eb1c[4];
#pragma unroll
    for (int t = 0; t < 4; ++t) eb1c[t] = *(const f32x4*)(eb1 + 16 * t + 4 * q);
    f32x4 eb2c[2];
#pragma unroll
    for (int mt = 0; mt < 2; ++mt) eb2c[mt] = *(const f32x4*)(eb2 + 16 * mt + 4 * q);
    f32x4 tbias;
    {
        float e0 = encfb[0], e1 = encfb[1], e2 = encfb[2];
        tbias[0] = q0 ? e0 : 0.f;
        tbias[1] = q0 ? e1 : 0.f;
        tbias[2] = q0 ? e2 : 0.f;
        tbias[3] = 0.f;
    }

    // ================== encoder: all-MFMA, no LDS ==================
    f32x4 acct[4];
#pragma unroll
    for (int nt = 0; nt < 4; ++nt) {
        int row = rowbase + 16 * nt + l15;
        row = row < n ? row : (n - 1);
        const float4 s = reinterpret_cast<const float4*>(states)[row];
        unsigned p01 = pack2(s.x, s.y);
        unsigned p23 = pack2(s.z, s.w);
        half8_t b1 = mk8(q0 ? p01 : 0u, q0 ? p23 : 0u, 0u, 0u);

        f32x4 acc1[4];
#pragma unroll
        for (int t = 0; t < 4; ++t)
            acc1[t] = __builtin_amdgcn_mfma_f32_16x16x32_f16(aF1[t], b1, eb1c[t], 0, 0, 0);

        half8_t b2f0 = mk8(relu2u(acc1[0][0], acc1[0][1]), relu2u(acc1[0][2], acc1[0][3]),
                           relu2u(acc1[1][0], acc1[1][1]), relu2u(acc1[1][2], acc1[1][3]));
        half8_t b2f1 = mk8(relu2u(acc1[2][0], acc1[2][1]), relu2u(acc1[2][2], acc1[2][3]),
                           relu2u(acc1[3][0], acc1[3][1]), relu2u(acc1[3][2], acc1[3][3]));

        f32x4 acc2[2];
#pragma unroll
        for (int mt = 0; mt < 2; ++mt) {
            f32x4 a = __builtin_amdgcn_mfma_f32_16x16x32_f16(aF2[mt * 2 + 0], b2f0, eb2c[mt], 0, 0, 0);
            acc2[mt] = __builtin_amdgcn_mfma_f32_16x16x32_f16(aF2[mt * 2 + 1], b2f1, a, 0, 0, 0);
        }

        half8_t btl = mk8(relu2u(acc2[0][0], acc2[0][1]), relu2u(acc2[0][2], acc2[0][3]),
                          relu2u(acc2[1][0], acc2[1][1]), relu2u(acc2[1][2], acc2[1][3]));

        acct[nt] = __builtin_amdgcn_mfma_f32_16x16x32_f16(aFt, btl, tbias, 0, 0, 0);
    }

    // redistribute x to owner lanes
    float x0, x1, x2;
    {
        int paddr = l15 * 4;
        float xr[3];
#pragma unroll
        for (int m = 0; m < 3; ++m) {
            float p0 = __int_as_float(__builtin_amdgcn_ds_bpermute(paddr, __float_as_int(acct[0][m])));
            float p1 = __int_as_float(__builtin_amdgcn_ds_bpermute(paddr, __float_as_int(acct[1][m])));
            float p2 = __int_as_float(__builtin_amdgcn_ds_bpermute(paddr, __float_as_int(acct[2][m])));
            float p3 = __int_as_float(__builtin_amdgcn_ds_bpermute(paddr, __float_as_int(acct[3][m])));
            float lo = (lane & 32) ? p2 : p0;
            float hi = (lane & 32) ? p3 : p1;
            xr[m] = (lane & 16) ? hi : lo;
        }
        x0 = xr[0]; x1 = xr[1]; x2 = xr[2];
    }

    // ================== MAF flow: even/odd split + LDS biases + y0-fold ==================
#pragma unroll
    for (int l = 0; l < 10; ++l) {
        const half2_t* w0e = (const half2_t*)(ws + OFF_FL + l * 80);
        const half2_t* w0o = (const half2_t*)(ws + OFF_FL + l * 80 + 8);
        const half2_t* w1o = (const half2_t*)(ws + OFF_FL + l * 80 + 16);
        const half2_t* m2e = (const half2_t*)(ws + OFF_FL + l * 80 + 24);
        const half2_t* m2o = (const half2_t*)(ws + OFF_FL + l * 80 + 32);
        const half2_t* a2e = (const half2_t*)(ws + OFF_FL + l * 80 + 40);
        const half2_t* a2o = (const half2_t*)(ws + OFF_FL + l * 80 + 48);
        const half2_t* m1w = (const half2_t*)(ws + OFF_FL + l * 80 + 56);
        const half2_t* a1w = (const half2_t*)(ws + OFF_FL + l * 80 + 64);

        const half2_t* bhe = (const half2_t*)(flds + l * 24);
        const half2_t* bho = (const half2_t*)(flds + l * 24 + 8);
        const float*   ini = (const float*)(flds + l * 24 + 16);

        half2_t x0d = __builtin_amdgcn_cvt_pkrtz(x0, x0);
        half2_t x1d = __builtin_amdgcn_cvt_pkrtz(x1, x1);
        half2_t z = {0, 0};

        half2_t he[8], ho[8];
#pragma unroll
        for (int p = 0; p < 8; ++p) {
            he[p] = __builtin_elementwise_max(
                        __builtin_elementwise_fma(x0d, w0e[p], bhe[p]), z);
            ho[p] = __builtin_elementwise_max(
                        __builtin_elementwise_fma(x0d, w0o[p],
                            __builtin_elementwise_fma(x1d, w1o[p], bho[p])), z);
        }

        float mu2 = ini[0], mu1 = ini[1], aa2 = ini[2], aa1 = ini[3];
#pragma unroll
        for (int p = 0; p < 8; ++p) {
            mu2 = __builtin_amdgcn_fdot2(he[p], m2e[p], mu2, false);
            mu2 = __builtin_amdgcn_fdot2(ho[p], m2o[p], mu2, false);
            aa2 = __builtin_amdgcn_fdot2(he[p], a2e[p], aa2, false);
            aa2 = __builtin_amdgcn_fdot2(ho[p], a2o[p], aa2, false);
            mu1 = __builtin_amdgcn_fdot2(he[p], m1w[p], mu1, false);
            aa1 = __builtin_amdgcn_fdot2(he[p], a1w[p], aa1, false);
        }

        float t1 = fast_tanh(aa1);
        float t2 = fast_tanh(aa2);
        float s2 = __expf(ini[4] - t2);   // c0_{l-1} * exp(-t2)
        float s1 = __expf(-t1);
        float y2 = (x2 - mu2) * s2;
        float y1 = (x1 - mu1) * s1;
        float nx2 = x0;                   // raw pass-through (affine deferred)
        x0 = y2; x1 = y1; x2 = nx2;
    }

    // pending layer-9 affine on the dim-0 slot (now in x2)
    {
        const float* fin = (const float*)(ws + OFF_FIN);
        x2 = (x2 - fin[0]) * fin[1];
    }

    // ================== squash + HSV ==================
    float u0 = fast_rcp(1.0f + __expf(-x0));
    float u1 = fast_rcp(1.0f + __expf(-x1));
    float u2 = fast_rcp(1.0f + __expf(-x2));

    if (i < n) {
        out[3 * i + 0] = TWO_PI_F * u0;
        out[3 * i + 1] = u1;
        out[3 * i + 2] = u2;
    }
}

extern "C" void kernel_launch(void* const* d_in, const int* in_sizes, int n_in,
                              void* d_out, int out_size, void* d_ws, size_t ws_size,
                              hipStream_t stream) {
    const float* states = (const float*)d_in[0];
    const float* ew1  = (const float*)d_in[1];
    const float* eb1  = (const float*)d_in[2];
    const float* ew2  = (const float*)d_in[3];
    const float* eb2  = (const float*)d_in[4];
    const float* ew3  = (const float*)d_in[5];
    const float* eb3  = (const float*)d_in[6];
    const float* pw   = (const float*)d_in[7];
    const float* pb   = (const float*)d_in[8];
    const float* fwh  = (const float*)d_in[9];
    const float* fbh  = (const float*)d_in[10];
    const float* fwmu = (const float*)d_in[11];
    const float* fbmu = (const float*)d_in[12];
    const float* fwa  = (const float*)d_in[13];
    const float* fba  = (const float*)d_in[14];
    float* out = (float*)d_out;
    unsigned* ws = (unsigned*)d_ws;

    gsi_setup<<<1, 256, 0, stream>>>(ew1, ew2, ew3, eb3, pw, pb,
                                     fwh, fbh, fwmu, fbmu, fwa, fba, ws);

    int n = in_sizes[0] / 4;
    int grid = (n + 255) / 256;
    gsi_kernel<<<grid, 256, 0, stream>>>(states, eb1, eb2, ws, out, n);
}